// Round 23
// baseline (143.863 us; speedup 1.0000x reference)
//
#include <hip/hip_runtime.h>
#include <hip/hip_bf16.h>
#include <stdint.h>

// Soft Decision Tree forward, MI355X (gfx950)
//   wsplit: W_inner -> Ws = bf16 [1024][800], bias[1024]    (validated)
//   gemm8 : P = sigmoid(bias + X @ Ws^T); 128x256 tile, 8x 64x64 waves, BK=32,
//           3-buf 72KB, 1 barrier/tile, fused f32->bf16 A-staging.
//           FIX vs r20/r22: NO register copy — AWRITE consumes `ac`, then
//           ALOAD(kt+2) reloads the SAME pair (dead after AWRITE). Only A-wait
//           is before AWRITE on loads issued a full iteration earlier.
//   tree  : r19-validated (shuffle-walk + wreg + dbuf reduce + bucketed atomics)
//   penalty: sums 32 buckets, then tree reduction           (validated)

#define BROWS 32768
#define KDIM  784
#define NNODE 1023
#define NP    1024
#define NLEAF 1024
#define OUTD  10
#define NDEPTH 10
#define LAMDA 1e-3f
#define NBKT  32            // leafsum buckets (blockIdx & 31)

#define GKW   800           // Ws row stride
#define NT    25            // K tiles of 32
#define BUFS  12288         // shorts per buffer (A 4096 + B 8192) = 24 KB

typedef __attribute__((ext_vector_type(8))) short short8;
typedef __attribute__((ext_vector_type(4))) float f32x4;

__device__ __forceinline__ unsigned short f2bf(float f) {
    unsigned int u = __float_as_uint(f);
    u = u + 0x7FFFu + ((u >> 16) & 1u);   // RNE
    return (unsigned short)(u >> 16);
}
__device__ __forceinline__ float bf2f(unsigned short h) {
    return __uint_as_float(((unsigned int)h) << 16);
}
__device__ __forceinline__ unsigned int pk2bf(float a, float b) {
    __hip_bfloat162 h = __float22bfloat162_rn(make_float2(a, b));   // v_cvt_pk_bf16_f32 (RNE)
    return *reinterpret_cast<unsigned int*>(&h);
}

// ============================ Pass W: cast W -> bf16 =============================
__global__ __launch_bounds__(256)
void sdt_wsplit(const float* __restrict__ Wi, unsigned short* __restrict__ Ws,
                float* __restrict__ bias)
{
    const int row = blockIdx.x;          // 0..1023
    const int tid = threadIdx.x;
    for (int c = tid; c < GKW; c += 256) {
        unsigned short v = 0;
        if (row < NNODE && c < KDIM) v = f2bf(Wi[(size_t)row * (KDIM + 1) + 1 + c]);
        Ws[(size_t)row * GKW + c] = v;
    }
    if (tid == 0) bias[row] = (row < NNODE) ? Wi[(size_t)row * (KDIM + 1)] : 0.f;
}

// ===== Pass A: 128x256 tile, 8 waves x 64x64, BK=32, 3-buffer, 1 barrier/tile =====
#define BAR() { __builtin_amdgcn_sched_barrier(0); __builtin_amdgcn_s_barrier(); __builtin_amdgcn_sched_barrier(0); }

// B staging: 2 x 16B global_load_lds per thread
#define STAGE_B(ktn, sel)                                                             \
    {                                                                                 \
        const int kk_ = (ktn) * 32;                                                   \
        unsigned short* bb_ = lds + (sel) * BUFS + 4096;                              \
        _Pragma("unroll")                                                             \
        for (int j = 0; j < 2; ++j)                                                   \
            __builtin_amdgcn_global_load_lds(                                         \
                (const __attribute__((address_space(1))) void*)(pB[j] + kk_),         \
                (__attribute__((address_space(3))) void*)(bb_ + (j * 512 + wave * 64) * 8), \
                16, 0, 0);                                                            \
    }

// A reg-load for tile ktn (per-half OOB clamp to col 0: zero-padded B -> 0 contrib)
#define ALOAD(ktn, d0, d1)                                                            \
    {                                                                                 \
        const int ca0_ = (ktn) * 32 + kcA * 8;                                        \
        const int cb0_ = ca0_ + 4;                                                    \
        const int ca_ = (ca0_ >= KDIM) ? 0 : ca0_;                                    \
        const int cb_ = (cb0_ >= KDIM) ? 0 : cb0_;                                    \
        d0 = *reinterpret_cast<const float4*>(pXrow + ca_);                           \
        d1 = *reinterpret_cast<const float4*>(pXrow + cb_);                           \
    }

// A cvt + LDS write: byte dest tid*16 within buffer sel (identical image to gload_lds)
#define AWRITE(sel, d0, d1)                                                           \
    {                                                                                 \
        unsigned short* ab_ = lds + (sel) * BUFS;                                     \
        union { short8 s; unsigned int u[4]; } t_;                                    \
        t_.u[0] = pk2bf(d0.x, d0.y); t_.u[1] = pk2bf(d0.z, d0.w);                     \
        t_.u[2] = pk2bf(d1.x, d1.y); t_.u[3] = pk2bf(d1.z, d1.w);                     \
        *reinterpret_cast<short8*>(ab_ + tid * 8) = t_.s;                             \
    }

// fragment reads: row stride 32 shorts (64B); slot swizzle q4 ^ ((row>>1)&3)
#define LDA4(dst, ab_)                                                                \
    _Pragma("unroll")                                                                 \
    for (int mi = 0; mi < 4; ++mi) {                                                  \
        const int row_ = wr * 64 + mi * 16 + fr;                                      \
        dst[mi] = *reinterpret_cast<const short8*>(                                   \
            (ab_) + row_ * 32 + ((q4 ^ ((row_ >> 1) & 3)) * 8));                      \
    }

#define LDB4(dst, bb_)                                                                \
    _Pragma("unroll")                                                                 \
    for (int n = 0; n < 4; ++n) {                                                     \
        const int row_ = wc * 64 + n * 16 + fr;                                       \
        dst[n] = *reinterpret_cast<const short8*>(                                    \
            (bb_) + row_ * 32 + ((q4 ^ ((row_ >> 1) & 3)) * 8));                      \
    }

#define MFMA16(av, bv)                                                                \
    _Pragma("unroll")                                                                 \
    for (int mi = 0; mi < 4; ++mi)                                                    \
        _Pragma("unroll")                                                             \
        for (int n = 0; n < 4; ++n)                                                   \
            acc[mi][n] = __builtin_amdgcn_mfma_f32_16x16x32_bf16(                     \
                av[mi], bv[n], acc[mi][n], 0, 0, 0);

__global__ __launch_bounds__(512, 4)
void sdt_gemm8(const float* __restrict__ X, const unsigned short* __restrict__ Ws,
               const float* __restrict__ bias, unsigned short* __restrict__ P)
{
    __shared__ __align__(16) unsigned short lds[36864];   // 72 KB = 3 x 24 KB

    const int tid  = threadIdx.x;
    const int wave = tid >> 6, lane = tid & 63;
    const int wr = wave >> 2, wc = wave & 3;              // 2x4 wave grid -> 64x64 per wave
    // XCD-aware swizzle: 1024 blocks, 128 contiguous per XCD (bijective)
    const int b  = blockIdx.x;
    const int wg = (b & 7) * 128 + (b >> 3);
    const int col0 = (wg & 3) * 256;                      // N (nodes): 4 tiles
    const int row0 = (wg >> 2) * 128;                     // M (batch): 256 tiles

    const int fr = lane & 15;
    const int q4 = lane >> 4;

    f32x4 acc[4][4];
#pragma unroll
    for (int i = 0; i < 4; ++i)
#pragma unroll
        for (int j = 0; j < 4; ++j) acc[i][j] = (f32x4)0.f;

    // A staging addressing: chunk c = tid -> r = c>>2, slot = c&3, kcA = slot ^ ((r>>1)&3)
    const int rA  = tid >> 2;
    const int kcA = (tid & 3) ^ ((rA >> 1) & 3);
    const float* pXrow = X + (size_t)(row0 + rA) * KDIM;

    const unsigned short* pB[2];
#pragma unroll
    for (int j = 0; j < 2; ++j) {
        const int c = j * 512 + tid;
        const int r = c >> 2;
        const int kc = (c & 3) ^ ((r >> 1) & 3);
        pB[j] = Ws + (size_t)(col0 + r) * GKW + kc * 8;
    }

    // prologue: tile 0 via throwaway pair; pipeline pair `ac` holds tile 1.
    float4 ac0, ac1;
    {
        float4 at0, at1;
        ALOAD(0, at0, at1);
        ALOAD(1, ac0, ac1);
        STAGE_B(0, 0);
        STAGE_B(1, 1);
        AWRITE(0, at0, at1);             // compiler drains ALOAD(0) via reg use
    }
    asm volatile("s_waitcnt vmcnt(2) lgkmcnt(0)" ::: "memory");   // B(0)+A(0) ready; B(1) in flight
    BAR();

    // K-loop, ONE barrier per tile (r19/r20 WAR ordering proof unchanged).
    // No copy: AWRITE consumes `ac` (tile kt+1, loaded a FULL iteration ago ->
    // its implicit wait never stalls), then ALOAD(kt+2) reloads `ac` (dead;
    // WAR safe by in-order issue). vmcnt(4) drains B(kt+1), leaves
    // {ALOAD(kt+2), B(kt+2)}; lgkmcnt(0) publishes the A ds_write.
#pragma unroll 1
    for (int kt = 0; kt < NT; ++kt) {
        const int cs = kt % 3;
        const unsigned short* ab = lds + cs * BUFS;
        const unsigned short* bb = ab + 4096;
        short8 a[4], bfr[4];
        LDA4(a, ab);
        LDB4(bfr, bb);
        if (kt + 1 < NT) AWRITE((kt + 1) % 3, ac0, ac1);
        if (kt + 2 < NT) {
            ALOAD(kt + 2, ac0, ac1);     // reload same pair (dead after AWRITE)
            STAGE_B(kt + 2, (kt + 2) % 3);
        }
        __builtin_amdgcn_s_setprio(1);
        MFMA16(a, bfr);
        __builtin_amdgcn_s_setprio(0);
        if (kt < NT - 3) { asm volatile("s_waitcnt vmcnt(4) lgkmcnt(0)" ::: "memory"); }
        else             { asm volatile("s_waitcnt vmcnt(0) lgkmcnt(0)" ::: "memory"); }
        BAR();
    }

    // ---- epilogue: bias + sigmoid, per-wave 8KB LDS transpose, coalesced stores ----
    __syncthreads();
    unsigned short* tr = lds + wave * 4096;   // 8 KB per wave (64 rows x 64 cols bf16)
    float bv[4];
#pragma unroll
    for (int n = 0; n < 4; ++n) bv[n] = bias[col0 + wc * 64 + n * 16 + fr];

#pragma unroll
    for (int m = 0; m < 4; ++m)
#pragma unroll
        for (int reg = 0; reg < 4; ++reg) {
            const int rl = m * 16 + q4 * 4 + reg;         // 0..63
#pragma unroll
            for (int n = 0; n < 4; ++n) {
                const float z = acc[m][n][reg] + bv[n];
                const float p = 1.f / (1.f + __expf(-z));
                tr[rl * 64 + n * 16 + fr] = f2bf(p);
            }
        }
    // wave-private readback (compiler inserts lgkm waits; no barrier needed)
#pragma unroll
    for (int it = 0; it < 8; ++it) {
        const int r  = it * 8 + (lane >> 3);
        const int c8 = (lane & 7) * 8;
        const uint4 v = *reinterpret_cast<const uint4*>(tr + r * 64 + c8);
        *reinterpret_cast<uint4*>(
            &P[(size_t)(row0 + wr * 64 + r) * NP + col0 + wc * 64 + c8]) = v;
    }
}

// ===================== Pass B: tree sweep + leaf GEMV + leaf sums =====================
// r19-validated. BYTE-IDENTICAL.
__global__ __launch_bounds__(256)
void sdt_tree(const unsigned short* __restrict__ P, const float* __restrict__ Wl,
              float* __restrict__ Y, float* __restrict__ leafsum32)
{
    __shared__ float rd[4][2][832];      // 26624 B (y reduction, stride 13, dbuf)
    __shared__ float lsb[4][1024];       // 16384 B (leaf-sum combine)
    const int tid = threadIdx.x;
    const int wave = tid >> 6, lane = tid & 63;

    float lsum[16];
#pragma unroll
    for (int i = 0; i < 16; ++i) lsum[i] = 0.f;

    float4 wreg[OUTD][4];
#pragma unroll
    for (int o = 0; o < OUTD; ++o)
#pragma unroll
        for (int i4 = 0; i4 < 4; ++i4)
            wreg[o][i4] = *reinterpret_cast<const float4*>(
                &Wl[o * NLEAF + lane * 16 + i4 * 4]);

    const int rowbase = blockIdx.x * 32 + wave * 8;
    const int o_r   = lane % 10;
    const int seg16 = (lane / 10) * 16;

#pragma unroll 2
    for (int r = 0; r < 8; ++r) {
        const int row = rowbase + r;
        const unsigned short* pr = P + (size_t)row * NP;
        float* rw = rd[wave][r & 1];      // row-parity double buffer

        const float preg = bf2f(pr[lane]);

        float mu = 1.f; int f = 0;
#pragma unroll
        for (int d = 0; d < 6; ++d) {
            const int bit = (lane >> (5 - d)) & 1;
            const float pv = __shfl(preg, f, 64);
            mu *= bit ? (1.f - pv) : pv;
            f = 2 * f + 1 + bit;
        }

        const float p6 = bf2f(pr[63 + lane]);
        float m1[2];
        m1[0] = mu * p6; m1[1] = mu * (1.f - p6);

        const unsigned int u7 = *reinterpret_cast<const unsigned int*>(pr + 128 + 2 * lane);
        const float lo7 = bf2f((unsigned short)(u7 & 0xffffu));
        const float hi7 = bf2f((unsigned short)(u7 >> 16));
        float e7 = __shfl_up(hi7, 1, 64);
        if (lane == 0) e7 = bf2f(pr[127]);
        float m2[4];
        m2[0] = m1[0] * e7;  m2[1] = m1[0] * (1.f - e7);
        m2[2] = m1[1] * lo7; m2[3] = m1[1] * (1.f - lo7);

        const uint2 u8 = *reinterpret_cast<const uint2*>(pr + 256 + 4 * lane);
        const float a0 = bf2f((unsigned short)(u8.x & 0xffffu));
        const float a1 = bf2f((unsigned short)(u8.x >> 16));
        const float a2 = bf2f((unsigned short)(u8.y & 0xffffu));
        const float a3 = bf2f((unsigned short)(u8.y >> 16));
        float e8 = __shfl_up(a3, 1, 64);
        if (lane == 0) e8 = bf2f(pr[255]);
        const float p8v[4] = {e8, a0, a1, a2};
        float m3[8];
#pragma unroll
        for (int i = 0; i < 4; ++i) {
            m3[2 * i] = m2[i] * p8v[i]; m3[2 * i + 1] = m2[i] * (1.f - p8v[i]);
        }

        const uint4 u9 = *reinterpret_cast<const uint4*>(pr + 512 + 8 * lane);
        const float b0 = bf2f((unsigned short)(u9.x & 0xffffu));
        const float b1 = bf2f((unsigned short)(u9.x >> 16));
        const float b2 = bf2f((unsigned short)(u9.y & 0xffffu));
        const float b3 = bf2f((unsigned short)(u9.y >> 16));
        const float b4 = bf2f((unsigned short)(u9.z & 0xffffu));
        const float b5 = bf2f((unsigned short)(u9.z >> 16));
        const float b6 = bf2f((unsigned short)(u9.w & 0xffffu));
        const float b7 = bf2f((unsigned short)(u9.w >> 16));
        float e9 = __shfl_up(b7, 1, 64);
        if (lane == 0) e9 = bf2f(pr[511]);
        const float p9v[8] = {e9, b0, b1, b2, b3, b4, b5, b6};
        float m4[16];
#pragma unroll
        for (int i = 0; i < 8; ++i) {
            m4[2 * i] = m3[i] * p9v[i]; m4[2 * i + 1] = m3[i] * (1.f - p9v[i]);
        }
#pragma unroll
        for (int i = 0; i < 16; ++i) lsum[i] += m4[i];

#pragma unroll
        for (int o = 0; o < OUTD; ++o) {
            float s = 0.f;
#pragma unroll
            for (int i4 = 0; i4 < 4; ++i4) {
                const float4 w4 = wreg[o][i4];
                s = fmaf(m4[4 * i4 + 0], w4.x, s);
                s = fmaf(m4[4 * i4 + 1], w4.y, s);
                s = fmaf(m4[4 * i4 + 2], w4.z, s);
                s = fmaf(m4[4 * i4 + 3], w4.w, s);
            }
            rw[lane * 13 + o] = s;
        }
        float s = 0.f;
        if (lane < 40) {
#pragma unroll
            for (int m = 0; m < 16; ++m) s += rw[(seg16 + m) * 13 + o_r];
        }
        s += __shfl_down(s, 20, 64);
        s += __shfl_down(s, 10, 64);
        if (lane < 10) Y[(size_t)row * OUTD + lane] = s;
    }

#pragma unroll
    for (int i = 0; i < 16; ++i) {
        const int ii = (i + lane) & 15;
        lsb[wave][lane * 16 + ii] = lsum[ii];
    }
    __syncthreads();
    float* bkt = leafsum32 + (size_t)(blockIdx.x & (NBKT - 1)) * NLEAF;
    for (int idx = tid; idx < NLEAF; idx += 256) {
        const float s = lsb[0][idx] + lsb[1][idx] + lsb[2][idx] + lsb[3][idx];
        atomicAdd(&bkt[idx], s);
    }
}

// ============================ Pass C: penalty ============================
__global__ __launch_bounds__(1024)
void sdt_penalty(const float* __restrict__ leafsum32, float* __restrict__ pen_out)
{
    __shared__ float t[NLEAF];
    __shared__ float red1[1024];
    const int tid = threadIdx.x;
    float accv = 0.f;
#pragma unroll
    for (int k = 0; k < NBKT; ++k) accv += leafsum32[k * NLEAF + tid];
    t[tid] = accv;
    __syncthreads();
    float pen = 0.f;
    for (int d = NDEPTH; d >= 1; --d) {
        const int n = 1 << d;
        if (tid < n) {
            const float num = t[tid];
            const float par = t[tid & ~1] + t[tid | 1];
            const float a = num / par;
            const float coeff = LAMDA * exp2f((float)(1 - d));
            pen -= 0.5f * coeff * (logf(a) + logf(1.f - a));
        }
        float s = 0.f;
        if (tid < (n >> 1)) s = t[2 * tid] + t[2 * tid + 1];
        __syncthreads();
        if (tid < (n >> 1)) t[tid] = s;
        __syncthreads();
    }
    red1[tid] = pen;
    __syncthreads();
    for (int off = 512; off >= 1; off >>= 1) {
        if (tid < off) red1[tid] += red1[tid + off];
        __syncthreads();
    }
    if (tid == 0) pen_out[0] = red1[0];
}

// ================================ launch ================================
extern "C" void kernel_launch(void* const* d_in, const int* in_sizes, int n_in,
                              void* d_out, int out_size, void* d_ws, size_t ws_size,
                              hipStream_t stream)
{
    const float* X  = (const float*)d_in[0];
    const float* Wi = (const float*)d_in[1];
    const float* Wl = (const float*)d_in[2];
    float* Y   = (float*)d_out;
    float* pen = Y + (size_t)BROWS * OUTD;

    char* ws = (char*)d_ws;
    const size_t P_BYTES  = (size_t)BROWS * NP * 2;            // 67,108,864
    const size_t WS_BYTES = (size_t)NP * GKW * 2;              // 1,638,400

    unsigned short* P   = (unsigned short*)ws;
    unsigned short* Wsp = (unsigned short*)(ws + P_BYTES);
    float* bias      = (float*)(ws + P_BYTES + WS_BYTES);
    float* leafsum32 = (float*)(ws + P_BYTES + WS_BYTES + 4096);  // 128 KB

    hipMemsetAsync(leafsum32, 0, NBKT * NLEAF * sizeof(float), stream);
    sdt_wsplit<<<1024, 256, 0, stream>>>(Wi, Wsp, bias);
    sdt_gemm8<<<1024, 512, 0, stream>>>(X, Wsp, bias, P);
    sdt_tree<<<BROWS / 32, 256, 0, stream>>>(P, Wl, Y, leafsum32);
    sdt_penalty<<<1, 1024, 0, stream>>>(leafsum32, pen);
}

// Round 24
// 143.324 us; speedup vs baseline: 1.0038x; 1.0038x over previous
//
#include <hip/hip_runtime.h>
#include <hip/hip_bf16.h>
#include <stdint.h>

// Soft Decision Tree forward, MI355X (gfx950)
//   wsplit: W_inner -> Ws = bf16 [1024][800], bias[1024]    (validated)
//   gemm8 : fused f32->bf16 A-staging, 128x256, 1 barrier/tile (r22/r23-validated)
//   tree  : occupancy build: shuffle-walk + GLOBAL Wl (r14-validated) + single
//           stride-13 reduce (r17-validated) + bucketed atomics (r17-validated).
//           wreg and rd-dbuf REMOVED (both measured ~neutral; cost 160 VGPR/13KB)
//   penalty: sums 32 buckets, then tree reduction           (validated)

#define BROWS 32768
#define KDIM  784
#define NNODE 1023
#define NP    1024
#define NLEAF 1024
#define OUTD  10
#define NDEPTH 10
#define LAMDA 1e-3f
#define NBKT  32            // leafsum buckets (blockIdx & 31)

#define GKW   800           // Ws row stride
#define NT    25            // K tiles of 32
#define BUFS  12288         // shorts per buffer (A 4096 + B 8192) = 24 KB

typedef __attribute__((ext_vector_type(8))) short short8;
typedef __attribute__((ext_vector_type(4))) float f32x4;

__device__ __forceinline__ unsigned short f2bf(float f) {
    unsigned int u = __float_as_uint(f);
    u = u + 0x7FFFu + ((u >> 16) & 1u);   // RNE
    return (unsigned short)(u >> 16);
}
__device__ __forceinline__ float bf2f(unsigned short h) {
    return __uint_as_float(((unsigned int)h) << 16);
}
__device__ __forceinline__ unsigned int pk2bf(float a, float b) {
    __hip_bfloat162 h = __float22bfloat162_rn(make_float2(a, b));   // v_cvt_pk_bf16_f32 (RNE)
    return *reinterpret_cast<unsigned int*>(&h);
}

// ============================ Pass W: cast W -> bf16 =============================
__global__ __launch_bounds__(256)
void sdt_wsplit(const float* __restrict__ Wi, unsigned short* __restrict__ Ws,
                float* __restrict__ bias)
{
    const int row = blockIdx.x;          // 0..1023
    const int tid = threadIdx.x;
    for (int c = tid; c < GKW; c += 256) {
        unsigned short v = 0;
        if (row < NNODE && c < KDIM) v = f2bf(Wi[(size_t)row * (KDIM + 1) + 1 + c]);
        Ws[(size_t)row * GKW + c] = v;
    }
    if (tid == 0) bias[row] = (row < NNODE) ? Wi[(size_t)row * (KDIM + 1)] : 0.f;
}

// ===== Pass A: 128x256 tile, 8 waves x 64x64, BK=32, 3-buffer, 1 barrier/tile =====
#define BAR() { __builtin_amdgcn_sched_barrier(0); __builtin_amdgcn_s_barrier(); __builtin_amdgcn_sched_barrier(0); }

#define STAGE_B(ktn, sel)                                                             \
    {                                                                                 \
        const int kk_ = (ktn) * 32;                                                   \
        unsigned short* bb_ = lds + (sel) * BUFS + 4096;                              \
        _Pragma("unroll")                                                             \
        for (int j = 0; j < 2; ++j)                                                   \
            __builtin_amdgcn_global_load_lds(                                         \
                (const __attribute__((address_space(1))) void*)(pB[j] + kk_),         \
                (__attribute__((address_space(3))) void*)(bb_ + (j * 512 + wave * 64) * 8), \
                16, 0, 0);                                                            \
    }

#define ALOAD(ktn, d0, d1)                                                            \
    {                                                                                 \
        const int ca0_ = (ktn) * 32 + kcA * 8;                                        \
        const int cb0_ = ca0_ + 4;                                                    \
        const int ca_ = (ca0_ >= KDIM) ? 0 : ca0_;                                    \
        const int cb_ = (cb0_ >= KDIM) ? 0 : cb0_;                                    \
        d0 = *reinterpret_cast<const float4*>(pXrow + ca_);                           \
        d1 = *reinterpret_cast<const float4*>(pXrow + cb_);                           \
    }

#define AWRITE(sel, d0, d1)                                                           \
    {                                                                                 \
        unsigned short* ab_ = lds + (sel) * BUFS;                                     \
        union { short8 s; unsigned int u[4]; } t_;                                    \
        t_.u[0] = pk2bf(d0.x, d0.y); t_.u[1] = pk2bf(d0.z, d0.w);                     \
        t_.u[2] = pk2bf(d1.x, d1.y); t_.u[3] = pk2bf(d1.z, d1.w);                     \
        *reinterpret_cast<short8*>(ab_ + tid * 8) = t_.s;                             \
    }

#define LDA4(dst, ab_)                                                                \
    _Pragma("unroll")                                                                 \
    for (int mi = 0; mi < 4; ++mi) {                                                  \
        const int row_ = wr * 64 + mi * 16 + fr;                                      \
        dst[mi] = *reinterpret_cast<const short8*>(                                   \
            (ab_) + row_ * 32 + ((q4 ^ ((row_ >> 1) & 3)) * 8));                      \
    }

#define LDB4(dst, bb_)                                                                \
    _Pragma("unroll")                                                                 \
    for (int n = 0; n < 4; ++n) {                                                     \
        const int row_ = wc * 64 + n * 16 + fr;                                       \
        dst[n] = *reinterpret_cast<const short8*>(                                    \
            (bb_) + row_ * 32 + ((q4 ^ ((row_ >> 1) & 3)) * 8));                      \
    }

#define MFMA16(av, bv)                                                                \
    _Pragma("unroll")                                                                 \
    for (int mi = 0; mi < 4; ++mi)                                                    \
        _Pragma("unroll")                                                             \
        for (int n = 0; n < 4; ++n)                                                   \
            acc[mi][n] = __builtin_amdgcn_mfma_f32_16x16x32_bf16(                     \
                av[mi], bv[n], acc[mi][n], 0, 0, 0);

__global__ __launch_bounds__(512, 4)
void sdt_gemm8(const float* __restrict__ X, const unsigned short* __restrict__ Ws,
               const float* __restrict__ bias, unsigned short* __restrict__ P)
{
    __shared__ __align__(16) unsigned short lds[36864];   // 72 KB = 3 x 24 KB

    const int tid  = threadIdx.x;
    const int wave = tid >> 6, lane = tid & 63;
    const int wr = wave >> 2, wc = wave & 3;
    const int b  = blockIdx.x;
    const int wg = (b & 7) * 128 + (b >> 3);
    const int col0 = (wg & 3) * 256;
    const int row0 = (wg >> 2) * 128;

    const int fr = lane & 15;
    const int q4 = lane >> 4;

    f32x4 acc[4][4];
#pragma unroll
    for (int i = 0; i < 4; ++i)
#pragma unroll
        for (int j = 0; j < 4; ++j) acc[i][j] = (f32x4)0.f;

    const int rA  = tid >> 2;
    const int kcA = (tid & 3) ^ ((rA >> 1) & 3);
    const float* pXrow = X + (size_t)(row0 + rA) * KDIM;

    const unsigned short* pB[2];
#pragma unroll
    for (int j = 0; j < 2; ++j) {
        const int c = j * 512 + tid;
        const int r = c >> 2;
        const int kc = (c & 3) ^ ((r >> 1) & 3);
        pB[j] = Ws + (size_t)(col0 + r) * GKW + kc * 8;
    }

    float4 ac0, ac1;
    {
        float4 at0, at1;
        ALOAD(0, at0, at1);
        ALOAD(1, ac0, ac1);
        STAGE_B(0, 0);
        STAGE_B(1, 1);
        AWRITE(0, at0, at1);
    }
    asm volatile("s_waitcnt vmcnt(2) lgkmcnt(0)" ::: "memory");
    BAR();

#pragma unroll 1
    for (int kt = 0; kt < NT; ++kt) {
        const int cs = kt % 3;
        const unsigned short* ab = lds + cs * BUFS;
        const unsigned short* bb = ab + 4096;
        short8 a[4], bfr[4];
        LDA4(a, ab);
        LDB4(bfr, bb);
        if (kt + 1 < NT) AWRITE((kt + 1) % 3, ac0, ac1);
        if (kt + 2 < NT) {
            ALOAD(kt + 2, ac0, ac1);
            STAGE_B(kt + 2, (kt + 2) % 3);
        }
        __builtin_amdgcn_s_setprio(1);
        MFMA16(a, bfr);
        __builtin_amdgcn_s_setprio(0);
        if (kt < NT - 3) { asm volatile("s_waitcnt vmcnt(4) lgkmcnt(0)" ::: "memory"); }
        else             { asm volatile("s_waitcnt vmcnt(0) lgkmcnt(0)" ::: "memory"); }
        BAR();
    }

    __syncthreads();
    unsigned short* tr = lds + wave * 4096;
    float bv[4];
#pragma unroll
    for (int n = 0; n < 4; ++n) bv[n] = bias[col0 + wc * 64 + n * 16 + fr];

#pragma unroll
    for (int m = 0; m < 4; ++m)
#pragma unroll
        for (int reg = 0; reg < 4; ++reg) {
            const int rl = m * 16 + q4 * 4 + reg;
#pragma unroll
            for (int n = 0; n < 4; ++n) {
                const float z = acc[m][n][reg] + bv[n];
                const float p = 1.f / (1.f + __expf(-z));
                tr[rl * 64 + n * 16 + fr] = f2bf(p);
            }
        }
#pragma unroll
    for (int it = 0; it < 8; ++it) {
        const int r  = it * 8 + (lane >> 3);
        const int c8 = (lane & 7) * 8;
        const uint4 v = *reinterpret_cast<const uint4*>(tr + r * 64 + c8);
        *reinterpret_cast<uint4*>(
            &P[(size_t)(row0 + wr * 64 + r) * NP + col0 + wc * 64 + c8]) = v;
    }
}

// ===================== Pass B: tree sweep + leaf GEMV + leaf sums =====================
// Occupancy build: shuffle-walk; Wl from GLOBAL (L2-resident, r14 form); single
// stride-13 rd (r17 form); bucketed atomics. LDS 29.7 KB, VGPR ~120 -> 4-5 blocks/CU.
__global__ __launch_bounds__(256)
void sdt_tree(const unsigned short* __restrict__ P, const float* __restrict__ Wl,
              float* __restrict__ Y, float* __restrict__ leafsum32)
{
    __shared__ float rd[4][832];         // 13312 B (y reduction, stride 13)
    __shared__ float lsb[4][1024];       // 16384 B (leaf-sum combine)
    const int tid = threadIdx.x;
    const int wave = tid >> 6, lane = tid & 63;

    float lsum[16];
#pragma unroll
    for (int i = 0; i < 16; ++i) lsum[i] = 0.f;

    float* rw = rd[wave];
    const int rowbase = blockIdx.x * 32 + wave * 8;
    const int o_r   = lane % 10;
    const int seg16 = (lane / 10) * 16;

#pragma unroll 2
    for (int r = 0; r < 8; ++r) {
        const int row = rowbase + r;
        const unsigned short* pr = P + (size_t)row * NP;

        const float preg = bf2f(pr[lane]);

        float mu = 1.f; int f = 0;
#pragma unroll
        for (int d = 0; d < 6; ++d) {
            const int bit = (lane >> (5 - d)) & 1;
            const float pv = __shfl(preg, f, 64);
            mu *= bit ? (1.f - pv) : pv;
            f = 2 * f + 1 + bit;
        }

        const float p6 = bf2f(pr[63 + lane]);
        float m1[2];
        m1[0] = mu * p6; m1[1] = mu * (1.f - p6);

        const unsigned int u7 = *reinterpret_cast<const unsigned int*>(pr + 128 + 2 * lane);
        const float lo7 = bf2f((unsigned short)(u7 & 0xffffu));
        const float hi7 = bf2f((unsigned short)(u7 >> 16));
        float e7 = __shfl_up(hi7, 1, 64);
        if (lane == 0) e7 = bf2f(pr[127]);
        float m2[4];
        m2[0] = m1[0] * e7;  m2[1] = m1[0] * (1.f - e7);
        m2[2] = m1[1] * lo7; m2[3] = m1[1] * (1.f - lo7);

        const uint2 u8 = *reinterpret_cast<const uint2*>(pr + 256 + 4 * lane);
        const float a0 = bf2f((unsigned short)(u8.x & 0xffffu));
        const float a1 = bf2f((unsigned short)(u8.x >> 16));
        const float a2 = bf2f((unsigned short)(u8.y & 0xffffu));
        const float a3 = bf2f((unsigned short)(u8.y >> 16));
        float e8 = __shfl_up(a3, 1, 64);
        if (lane == 0) e8 = bf2f(pr[255]);
        const float p8v[4] = {e8, a0, a1, a2};
        float m3[8];
#pragma unroll
        for (int i = 0; i < 4; ++i) {
            m3[2 * i] = m2[i] * p8v[i]; m3[2 * i + 1] = m2[i] * (1.f - p8v[i]);
        }

        const uint4 u9 = *reinterpret_cast<const uint4*>(pr + 512 + 8 * lane);
        const float b0 = bf2f((unsigned short)(u9.x & 0xffffu));
        const float b1 = bf2f((unsigned short)(u9.x >> 16));
        const float b2 = bf2f((unsigned short)(u9.y & 0xffffu));
        const float b3 = bf2f((unsigned short)(u9.y >> 16));
        const float b4 = bf2f((unsigned short)(u9.z & 0xffffu));
        const float b5 = bf2f((unsigned short)(u9.z >> 16));
        const float b6 = bf2f((unsigned short)(u9.w & 0xffffu));
        const float b7 = bf2f((unsigned short)(u9.w >> 16));
        float e9 = __shfl_up(b7, 1, 64);
        if (lane == 0) e9 = bf2f(pr[511]);
        const float p9v[8] = {e9, b0, b1, b2, b3, b4, b5, b6};
        float m4[16];
#pragma unroll
        for (int i = 0; i < 8; ++i) {
            m4[2 * i] = m3[i] * p9v[i]; m4[2 * i + 1] = m3[i] * (1.f - p9v[i]);
        }
#pragma unroll
        for (int i = 0; i < 16; ++i) lsum[i] += m4[i];

        // y partials: Wl from global (L2-resident)
#pragma unroll
        for (int o = 0; o < OUTD; ++o) {
            float s = 0.f;
#pragma unroll
            for (int i4 = 0; i4 < 4; ++i4) {
                const float4 w4 = *reinterpret_cast<const float4*>(
                    &Wl[o * NLEAF + lane * 16 + i4 * 4]);
                s = fmaf(m4[4 * i4 + 0], w4.x, s);
                s = fmaf(m4[4 * i4 + 1], w4.y, s);
                s = fmaf(m4[4 * i4 + 2], w4.z, s);
                s = fmaf(m4[4 * i4 + 3], w4.w, s);
            }
            rw[lane * 13 + o] = s;
        }
        float s = 0.f;
        if (lane < 40) {
#pragma unroll
            for (int m = 0; m < 16; ++m) s += rw[(seg16 + m) * 13 + o_r];
        }
        s += __shfl_down(s, 20, 64);
        s += __shfl_down(s, 10, 64);
        if (lane < 10) Y[(size_t)row * OUTD + lane] = s;
    }

#pragma unroll
    for (int i = 0; i < 16; ++i) {
        const int ii = (i + lane) & 15;
        lsb[wave][lane * 16 + ii] = lsum[ii];
    }
    __syncthreads();
    float* bkt = leafsum32 + (size_t)(blockIdx.x & (NBKT - 1)) * NLEAF;
    for (int idx = tid; idx < NLEAF; idx += 256) {
        const float s = lsb[0][idx] + lsb[1][idx] + lsb[2][idx] + lsb[3][idx];
        atomicAdd(&bkt[idx], s);
    }
}

// ============================ Pass C: penalty ============================
__global__ __launch_bounds__(1024)
void sdt_penalty(const float* __restrict__ leafsum32, float* __restrict__ pen_out)
{
    __shared__ float t[NLEAF];
    __shared__ float red1[1024];
    const int tid = threadIdx.x;
    float accv = 0.f;
#pragma unroll
    for (int k = 0; k < NBKT; ++k) accv += leafsum32[k * NLEAF + tid];
    t[tid] = accv;
    __syncthreads();
    float pen = 0.f;
    for (int d = NDEPTH; d >= 1; --d) {
        const int n = 1 << d;
        if (tid < n) {
            const float num = t[tid];
            const float par = t[tid & ~1] + t[tid | 1];
            const float a = num / par;
            const float coeff = LAMDA * exp2f((float)(1 - d));
            pen -= 0.5f * coeff * (logf(a) + logf(1.f - a));
        }
        float s = 0.f;
        if (tid < (n >> 1)) s = t[2 * tid] + t[2 * tid + 1];
        __syncthreads();
        if (tid < (n >> 1)) t[tid] = s;
        __syncthreads();
    }
    red1[tid] = pen;
    __syncthreads();
    for (int off = 512; off >= 1; off >>= 1) {
        if (tid < off) red1[tid] += red1[tid + off];
        __syncthreads();
    }
    if (tid == 0) pen_out[0] = red1[0];
}

// ================================ launch ================================
extern "C" void kernel_launch(void* const* d_in, const int* in_sizes, int n_in,
                              void* d_out, int out_size, void* d_ws, size_t ws_size,
                              hipStream_t stream)
{
    const float* X  = (const float*)d_in[0];
    const float* Wi = (const float*)d_in[1];
    const float* Wl = (const float*)d_in[2];
    float* Y   = (float*)d_out;
    float* pen = Y + (size_t)BROWS * OUTD;

    char* ws = (char*)d_ws;
    const size_t P_BYTES  = (size_t)BROWS * NP * 2;            // 67,108,864
    const size_t WS_BYTES = (size_t)NP * GKW * 2;              // 1,638,400

    unsigned short* P   = (unsigned short*)ws;
    unsigned short* Wsp = (unsigned short*)(ws + P_BYTES);
    float* bias      = (float*)(ws + P_BYTES + WS_BYTES);
    float* leafsum32 = (float*)(ws + P_BYTES + WS_BYTES + 4096);  // 128 KB

    hipMemsetAsync(leafsum32, 0, NBKT * NLEAF * sizeof(float), stream);
    sdt_wsplit<<<1024, 256, 0, stream>>>(Wi, Wsp, bias);
    sdt_gemm8<<<1024, 512, 0, stream>>>(X, Wsp, bias, P);
    sdt_tree<<<BROWS / 32, 256, 0, stream>>>(P, Wl, Y, leafsum32);
    sdt_penalty<<<1, 1024, 0, stream>>>(leafsum32, pen);
}

// Round 25
// 140.275 us; speedup vs baseline: 1.0256x; 1.0217x over previous
//
#include <hip/hip_runtime.h>
#include <hip/hip_bf16.h>
#include <stdint.h>

// Soft Decision Tree forward, MI355X (gfx950)
//   wsplit: W_inner -> Ws bf16 + bias; CHANGE: 32 extra blocks zero leafsum32
//           (hipMemsetAsync dispatch removed)
//   gemm8 : fused f32->bf16 A-staging, 128x256, 1 barrier/tile (r22-r24-validated)
//   tree  : r24-validated (shuffle-walk + global Wl + single rd + bucketed atomics)
//   penalty: sums 32 buckets, then tree reduction           (validated)

#define BROWS 32768
#define KDIM  784
#define NNODE 1023
#define NP    1024
#define NLEAF 1024
#define OUTD  10
#define NDEPTH 10
#define LAMDA 1e-3f
#define NBKT  32            // leafsum buckets (blockIdx & 31)

#define GKW   800           // Ws row stride
#define NT    25            // K tiles of 32
#define BUFS  12288         // shorts per buffer (A 4096 + B 8192) = 24 KB

typedef __attribute__((ext_vector_type(8))) short short8;
typedef __attribute__((ext_vector_type(4))) float f32x4;

__device__ __forceinline__ unsigned short f2bf(float f) {
    unsigned int u = __float_as_uint(f);
    u = u + 0x7FFFu + ((u >> 16) & 1u);   // RNE
    return (unsigned short)(u >> 16);
}
__device__ __forceinline__ float bf2f(unsigned short h) {
    return __uint_as_float(((unsigned int)h) << 16);
}
__device__ __forceinline__ unsigned int pk2bf(float a, float b) {
    __hip_bfloat162 h = __float22bfloat162_rn(make_float2(a, b));   // v_cvt_pk_bf16_f32 (RNE)
    return *reinterpret_cast<unsigned int*>(&h);
}

// ============== Pass W: cast W -> bf16 (+ leafsum zeroing in blocks >= 1024) ==============
__global__ __launch_bounds__(256)
void sdt_wsplit(const float* __restrict__ Wi, unsigned short* __restrict__ Ws,
                float* __restrict__ bias, float* __restrict__ leafsum32)
{
    const int b   = blockIdx.x;
    const int tid = threadIdx.x;
    if (b >= 1024) {
        // zero one 4 KB bucket: 1024 floats = 256 threads x 1 uint4
        uint4* dst = reinterpret_cast<uint4*>(leafsum32 + (size_t)(b - 1024) * NLEAF);
        dst[tid] = make_uint4(0u, 0u, 0u, 0u);
        return;
    }
    const int row = b;                   // 0..1023
    for (int c = tid; c < GKW; c += 256) {
        unsigned short v = 0;
        if (row < NNODE && c < KDIM) v = f2bf(Wi[(size_t)row * (KDIM + 1) + 1 + c]);
        Ws[(size_t)row * GKW + c] = v;
    }
    if (tid == 0) bias[row] = (row < NNODE) ? Wi[(size_t)row * (KDIM + 1)] : 0.f;
}

// ===== Pass A: 128x256 tile, 8 waves x 64x64, BK=32, 3-buffer, 1 barrier/tile =====
#define BAR() { __builtin_amdgcn_sched_barrier(0); __builtin_amdgcn_s_barrier(); __builtin_amdgcn_sched_barrier(0); }

#define STAGE_B(ktn, sel)                                                             \
    {                                                                                 \
        const int kk_ = (ktn) * 32;                                                   \
        unsigned short* bb_ = lds + (sel) * BUFS + 4096;                              \
        _Pragma("unroll")                                                             \
        for (int j = 0; j < 2; ++j)                                                   \
            __builtin_amdgcn_global_load_lds(                                         \
                (const __attribute__((address_space(1))) void*)(pB[j] + kk_),         \
                (__attribute__((address_space(3))) void*)(bb_ + (j * 512 + wave * 64) * 8), \
                16, 0, 0);                                                            \
    }

#define ALOAD(ktn, d0, d1)                                                            \
    {                                                                                 \
        const int ca0_ = (ktn) * 32 + kcA * 8;                                        \
        const int cb0_ = ca0_ + 4;                                                    \
        const int ca_ = (ca0_ >= KDIM) ? 0 : ca0_;                                    \
        const int cb_ = (cb0_ >= KDIM) ? 0 : cb0_;                                    \
        d0 = *reinterpret_cast<const float4*>(pXrow + ca_);                           \
        d1 = *reinterpret_cast<const float4*>(pXrow + cb_);                           \
    }

#define AWRITE(sel, d0, d1)                                                           \
    {                                                                                 \
        unsigned short* ab_ = lds + (sel) * BUFS;                                     \
        union { short8 s; unsigned int u[4]; } t_;                                    \
        t_.u[0] = pk2bf(d0.x, d0.y); t_.u[1] = pk2bf(d0.z, d0.w);                     \
        t_.u[2] = pk2bf(d1.x, d1.y); t_.u[3] = pk2bf(d1.z, d1.w);                     \
        *reinterpret_cast<short8*>(ab_ + tid * 8) = t_.s;                             \
    }

#define LDA4(dst, ab_)                                                                \
    _Pragma("unroll")                                                                 \
    for (int mi = 0; mi < 4; ++mi) {                                                  \
        const int row_ = wr * 64 + mi * 16 + fr;                                      \
        dst[mi] = *reinterpret_cast<const short8*>(                                   \
            (ab_) + row_ * 32 + ((q4 ^ ((row_ >> 1) & 3)) * 8));                      \
    }

#define LDB4(dst, bb_)                                                                \
    _Pragma("unroll")                                                                 \
    for (int n = 0; n < 4; ++n) {                                                     \
        const int row_ = wc * 64 + n * 16 + fr;                                       \
        dst[n] = *reinterpret_cast<const short8*>(                                    \
            (bb_) + row_ * 32 + ((q4 ^ ((row_ >> 1) & 3)) * 8));                      \
    }

#define MFMA16(av, bv)                                                                \
    _Pragma("unroll")                                                                 \
    for (int mi = 0; mi < 4; ++mi)                                                    \
        _Pragma("unroll")                                                             \
        for (int n = 0; n < 4; ++n)                                                   \
            acc[mi][n] = __builtin_amdgcn_mfma_f32_16x16x32_bf16(                     \
                av[mi], bv[n], acc[mi][n], 0, 0, 0);

__global__ __launch_bounds__(512, 4)
void sdt_gemm8(const float* __restrict__ X, const unsigned short* __restrict__ Ws,
               const float* __restrict__ bias, unsigned short* __restrict__ P)
{
    __shared__ __align__(16) unsigned short lds[36864];   // 72 KB = 3 x 24 KB

    const int tid  = threadIdx.x;
    const int wave = tid >> 6, lane = tid & 63;
    const int wr = wave >> 2, wc = wave & 3;
    const int b  = blockIdx.x;
    const int wg = (b & 7) * 128 + (b >> 3);
    const int col0 = (wg & 3) * 256;
    const int row0 = (wg >> 2) * 128;

    const int fr = lane & 15;
    const int q4 = lane >> 4;

    f32x4 acc[4][4];
#pragma unroll
    for (int i = 0; i < 4; ++i)
#pragma unroll
        for (int j = 0; j < 4; ++j) acc[i][j] = (f32x4)0.f;

    const int rA  = tid >> 2;
    const int kcA = (tid & 3) ^ ((rA >> 1) & 3);
    const float* pXrow = X + (size_t)(row0 + rA) * KDIM;

    const unsigned short* pB[2];
#pragma unroll
    for (int j = 0; j < 2; ++j) {
        const int c = j * 512 + tid;
        const int r = c >> 2;
        const int kc = (c & 3) ^ ((r >> 1) & 3);
        pB[j] = Ws + (size_t)(col0 + r) * GKW + kc * 8;
    }

    float4 ac0, ac1;
    {
        float4 at0, at1;
        ALOAD(0, at0, at1);
        ALOAD(1, ac0, ac1);
        STAGE_B(0, 0);
        STAGE_B(1, 1);
        AWRITE(0, at0, at1);
    }
    asm volatile("s_waitcnt vmcnt(2) lgkmcnt(0)" ::: "memory");
    BAR();

#pragma unroll 1
    for (int kt = 0; kt < NT; ++kt) {
        const int cs = kt % 3;
        const unsigned short* ab = lds + cs * BUFS;
        const unsigned short* bb = ab + 4096;
        short8 a[4], bfr[4];
        LDA4(a, ab);
        LDB4(bfr, bb);
        if (kt + 1 < NT) AWRITE((kt + 1) % 3, ac0, ac1);
        if (kt + 2 < NT) {
            ALOAD(kt + 2, ac0, ac1);
            STAGE_B(kt + 2, (kt + 2) % 3);
        }
        __builtin_amdgcn_s_setprio(1);
        MFMA16(a, bfr);
        __builtin_amdgcn_s_setprio(0);
        if (kt < NT - 3) { asm volatile("s_waitcnt vmcnt(4) lgkmcnt(0)" ::: "memory"); }
        else             { asm volatile("s_waitcnt vmcnt(0) lgkmcnt(0)" ::: "memory"); }
        BAR();
    }

    __syncthreads();
    unsigned short* tr = lds + wave * 4096;
    float bv[4];
#pragma unroll
    for (int n = 0; n < 4; ++n) bv[n] = bias[col0 + wc * 64 + n * 16 + fr];

#pragma unroll
    for (int m = 0; m < 4; ++m)
#pragma unroll
        for (int reg = 0; reg < 4; ++reg) {
            const int rl = m * 16 + q4 * 4 + reg;
#pragma unroll
            for (int n = 0; n < 4; ++n) {
                const float z = acc[m][n][reg] + bv[n];
                const float p = 1.f / (1.f + __expf(-z));
                tr[rl * 64 + n * 16 + fr] = f2bf(p);
            }
        }
#pragma unroll
    for (int it = 0; it < 8; ++it) {
        const int r  = it * 8 + (lane >> 3);
        const int c8 = (lane & 7) * 8;
        const uint4 v = *reinterpret_cast<const uint4*>(tr + r * 64 + c8);
        *reinterpret_cast<uint4*>(
            &P[(size_t)(row0 + wr * 64 + r) * NP + col0 + wc * 64 + c8]) = v;
    }
}

// ===================== Pass B: tree sweep + leaf GEMV + leaf sums =====================
// r24-validated. BYTE-IDENTICAL.
__global__ __launch_bounds__(256)
void sdt_tree(const unsigned short* __restrict__ P, const float* __restrict__ Wl,
              float* __restrict__ Y, float* __restrict__ leafsum32)
{
    __shared__ float rd[4][832];         // 13312 B (y reduction, stride 13)
    __shared__ float lsb[4][1024];       // 16384 B (leaf-sum combine)
    const int tid = threadIdx.x;
    const int wave = tid >> 6, lane = tid & 63;

    float lsum[16];
#pragma unroll
    for (int i = 0; i < 16; ++i) lsum[i] = 0.f;

    float* rw = rd[wave];
    const int rowbase = blockIdx.x * 32 + wave * 8;
    const int o_r   = lane % 10;
    const int seg16 = (lane / 10) * 16;

#pragma unroll 2
    for (int r = 0; r < 8; ++r) {
        const int row = rowbase + r;
        const unsigned short* pr = P + (size_t)row * NP;

        const float preg = bf2f(pr[lane]);

        float mu = 1.f; int f = 0;
#pragma unroll
        for (int d = 0; d < 6; ++d) {
            const int bit = (lane >> (5 - d)) & 1;
            const float pv = __shfl(preg, f, 64);
            mu *= bit ? (1.f - pv) : pv;
            f = 2 * f + 1 + bit;
        }

        const float p6 = bf2f(pr[63 + lane]);
        float m1[2];
        m1[0] = mu * p6; m1[1] = mu * (1.f - p6);

        const unsigned int u7 = *reinterpret_cast<const unsigned int*>(pr + 128 + 2 * lane);
        const float lo7 = bf2f((unsigned short)(u7 & 0xffffu));
        const float hi7 = bf2f((unsigned short)(u7 >> 16));
        float e7 = __shfl_up(hi7, 1, 64);
        if (lane == 0) e7 = bf2f(pr[127]);
        float m2[4];
        m2[0] = m1[0] * e7;  m2[1] = m1[0] * (1.f - e7);
        m2[2] = m1[1] * lo7; m2[3] = m1[1] * (1.f - lo7);

        const uint2 u8 = *reinterpret_cast<const uint2*>(pr + 256 + 4 * lane);
        const float a0 = bf2f((unsigned short)(u8.x & 0xffffu));
        const float a1 = bf2f((unsigned short)(u8.x >> 16));
        const float a2 = bf2f((unsigned short)(u8.y & 0xffffu));
        const float a3 = bf2f((unsigned short)(u8.y >> 16));
        float e8 = __shfl_up(a3, 1, 64);
        if (lane == 0) e8 = bf2f(pr[255]);
        const float p8v[4] = {e8, a0, a1, a2};
        float m3[8];
#pragma unroll
        for (int i = 0; i < 4; ++i) {
            m3[2 * i] = m2[i] * p8v[i]; m3[2 * i + 1] = m2[i] * (1.f - p8v[i]);
        }

        const uint4 u9 = *reinterpret_cast<const uint4*>(pr + 512 + 8 * lane);
        const float b0 = bf2f((unsigned short)(u9.x & 0xffffu));
        const float b1 = bf2f((unsigned short)(u9.x >> 16));
        const float b2 = bf2f((unsigned short)(u9.y & 0xffffu));
        const float b3 = bf2f((unsigned short)(u9.y >> 16));
        const float b4 = bf2f((unsigned short)(u9.z & 0xffffu));
        const float b5 = bf2f((unsigned short)(u9.z >> 16));
        const float b6 = bf2f((unsigned short)(u9.w & 0xffffu));
        const float b7 = bf2f((unsigned short)(u9.w >> 16));
        float e9 = __shfl_up(b7, 1, 64);
        if (lane == 0) e9 = bf2f(pr[511]);
        const float p9v[8] = {e9, b0, b1, b2, b3, b4, b5, b6};
        float m4[16];
#pragma unroll
        for (int i = 0; i < 8; ++i) {
            m4[2 * i] = m3[i] * p9v[i]; m4[2 * i + 1] = m3[i] * (1.f - p9v[i]);
        }
#pragma unroll
        for (int i = 0; i < 16; ++i) lsum[i] += m4[i];

#pragma unroll
        for (int o = 0; o < OUTD; ++o) {
            float s = 0.f;
#pragma unroll
            for (int i4 = 0; i4 < 4; ++i4) {
                const float4 w4 = *reinterpret_cast<const float4*>(
                    &Wl[o * NLEAF + lane * 16 + i4 * 4]);
                s = fmaf(m4[4 * i4 + 0], w4.x, s);
                s = fmaf(m4[4 * i4 + 1], w4.y, s);
                s = fmaf(m4[4 * i4 + 2], w4.z, s);
                s = fmaf(m4[4 * i4 + 3], w4.w, s);
            }
            rw[lane * 13 + o] = s;
        }
        float s = 0.f;
        if (lane < 40) {
#pragma unroll
            for (int m = 0; m < 16; ++m) s += rw[(seg16 + m) * 13 + o_r];
        }
        s += __shfl_down(s, 20, 64);
        s += __shfl_down(s, 10, 64);
        if (lane < 10) Y[(size_t)row * OUTD + lane] = s;
    }

#pragma unroll
    for (int i = 0; i < 16; ++i) {
        const int ii = (i + lane) & 15;
        lsb[wave][lane * 16 + ii] = lsum[ii];
    }
    __syncthreads();
    float* bkt = leafsum32 + (size_t)(blockIdx.x & (NBKT - 1)) * NLEAF;
    for (int idx = tid; idx < NLEAF; idx += 256) {
        const float s = lsb[0][idx] + lsb[1][idx] + lsb[2][idx] + lsb[3][idx];
        atomicAdd(&bkt[idx], s);
    }
}

// ============================ Pass C: penalty ============================
__global__ __launch_bounds__(1024)
void sdt_penalty(const float* __restrict__ leafsum32, float* __restrict__ pen_out)
{
    __shared__ float t[NLEAF];
    __shared__ float red1[1024];
    const int tid = threadIdx.x;
    float accv = 0.f;
#pragma unroll
    for (int k = 0; k < NBKT; ++k) accv += leafsum32[k * NLEAF + tid];
    t[tid] = accv;
    __syncthreads();
    float pen = 0.f;
    for (int d = NDEPTH; d >= 1; --d) {
        const int n = 1 << d;
        if (tid < n) {
            const float num = t[tid];
            const float par = t[tid & ~1] + t[tid | 1];
            const float a = num / par;
            const float coeff = LAMDA * exp2f((float)(1 - d));
            pen -= 0.5f * coeff * (logf(a) + logf(1.f - a));
        }
        float s = 0.f;
        if (tid < (n >> 1)) s = t[2 * tid] + t[2 * tid + 1];
        __syncthreads();
        if (tid < (n >> 1)) t[tid] = s;
        __syncthreads();
    }
    red1[tid] = pen;
    __syncthreads();
    for (int off = 512; off >= 1; off >>= 1) {
        if (tid < off) red1[tid] += red1[tid + off];
        __syncthreads();
    }
    if (tid == 0) pen_out[0] = red1[0];
}

// ================================ launch ================================
extern "C" void kernel_launch(void* const* d_in, const int* in_sizes, int n_in,
                              void* d_out, int out_size, void* d_ws, size_t ws_size,
                              hipStream_t stream)
{
    const float* X  = (const float*)d_in[0];
    const float* Wi = (const float*)d_in[1];
    const float* Wl = (const float*)d_in[2];
    float* Y   = (float*)d_out;
    float* pen = Y + (size_t)BROWS * OUTD;

    char* ws = (char*)d_ws;
    const size_t P_BYTES  = (size_t)BROWS * NP * 2;            // 67,108,864
    const size_t WS_BYTES = (size_t)NP * GKW * 2;              // 1,638,400

    unsigned short* P   = (unsigned short*)ws;
    unsigned short* Wsp = (unsigned short*)(ws + P_BYTES);
    float* bias      = (float*)(ws + P_BYTES + WS_BYTES);
    float* leafsum32 = (float*)(ws + P_BYTES + WS_BYTES + 4096);  // 128 KB

    sdt_wsplit<<<1024 + NBKT, 256, 0, stream>>>(Wi, Wsp, bias, leafsum32);
    sdt_gemm8<<<1024, 512, 0, stream>>>(X, Wsp, bias, P);
    sdt_tree<<<BROWS / 32, 256, 0, stream>>>(P, Wl, Y, leafsum32);
    sdt_penalty<<<1, 1024, 0, stream>>>(leafsum32, pen);
}